// Round 9
// baseline (134.645 us; speedup 1.0000x reference)
//
#include <hip/hip_runtime.h>

// Problem constants:
// inputs: (B=8, C=2, D=96, H=64, W=64) f32
// weight/bias: (F=8, C=2, d=3, h=60, w=64) f32
// out: (B=8, F=8, Dout=94, h=60, w=64) f32
#define B_ 8
#define C_ 2
#define D_ 96
#define H_ 64
#define W_ 64
#define F_ 8
#define KD 3
#define h_ 60
#define Dout_ 94
#define PLANE (h_ * W_)          // 3840 floats
#define NCH (PLANE / 4)          // 960 float4 chunks
#define TD 4                     // douts batched per block (ONE barrier per batch)
#define NTILE ((Dout_ + TD - 1) / TD)  // 24
#define NS2 (B_ * C_ * D_)       // 1536 s2 planes
#define S2_FLOATS ((size_t)NS2 * PLANE)

__device__ __forceinline__ void fma4(float4& a, const float4 v, const float4 g) {
    a.x += v.x * g.x; a.y += v.y * g.y;
    a.z += v.z * g.z; a.w += v.w * g.w;
}

__device__ __forceinline__ void add4(float4& a, const float4 v) {
    a.x += v.x; a.y += v.y; a.z += v.z; a.w += v.w;
}

// Horizontal 3-tap sum via lane shuffles; col4 = position 0..15 within a
// 16-lane row group. Boundary cols contribute zero. All 64 lanes must execute.
__device__ __forceinline__ float4 hsum3(float4 V, int col4) {
    const int lane = threadIdx.x & 63;
    float lw = __shfl(V.w, (lane + 63) & 63, 64);
    float rx = __shfl(V.x, (lane + 1) & 63, 64);
    if (col4 == 0) lw = 0.f;
    if (col4 == 15) rx = 0.f;
    float4 o;
    o.x = lw + V.x + V.y;
    o.y = V.x + V.y + V.z;
    o.z = V.y + V.z + V.w;
    o.w = V.z + V.w + rx;
    return o;
}

// ---------------------------------------------------------------------------
// Prep kernel (R9: S2 blocks XCD-pinned to their consumer).
// Blocks 0..NS2-1: S2[b,c,p] = vertical 5-sum of input plane (no LDS/barrier).
//   R9 remap: block index bx -> b = bx&7, j = bx>>3, c = j/D, p = j%D, so
//   bx % 8 == b. With index-round-robin block->XCD dispatch, every S2[b]
//   plane is PRODUCED on XCD b — the same XCD where k_main (b = bx&7)
//   CONSUMES it. S2[b] = 2.95 MB < 4 MB L2 -> k_main's S2 reads become
//   local-L2 hits instead of HBM/L3 fetches. Bijective remap, work unchanged.
// Blocks NS2..NS2+F_-1: BoxBS[f] = Box3x3( sum_{c,z} bias[f,c,z] ) (unchanged).
// ---------------------------------------------------------------------------
__global__ __launch_bounds__(256) void k_prep(const float* __restrict__ in,
                                              const float* __restrict__ bs,
                                              float* __restrict__ s2,
                                              float* __restrict__ bb) {
    const int bx = blockIdx.x;
    const int tid = threadIdx.x;
    __shared__ float4 lds[H_ * 16];  // used by bias path only (16 KB)

    if (bx < NS2) {
        const int b = bx & 7;             // XCD-pinned batch (matches k_main)
        const int j = bx >> 3;            // 0..191
        const int c = j / D_;             // 0..1
        const int p = j - c * D_;         // 0..95
        const int plane = (b * C_ + c) * D_ + p;

        const int col4 = tid & 15;
        const int seg = tid >> 4;         // 0..15; seg 15 idle (15*4 = 60 rows)
        if (seg >= 15) return;
        const int r0 = seg * 4;
        const float4* ip4 = (const float4*)(in + (size_t)plane * (H_ * W_));
        float4* op4 = (float4*)(s2 + (size_t)plane * PLANE);
        float4 v[8];
#pragma unroll
        for (int j8 = 0; j8 < 8; ++j8) v[j8] = ip4[(r0 + j8) * 16 + col4];
#pragma unroll
        for (int r = 0; r < 4; ++r) {
            float4 s = v[r];
#pragma unroll
            for (int j5 = 1; j5 < 5; ++j5) add4(s, v[r + j5]);
            op4[(r0 + r) * 16 + col4] = s;
        }
    } else {
        const int f = bx - NS2;
        float4* R = lds;  // rows 0..61, rows 0 and 61 zero
        if (tid < 32) {
            const int r = (tid >> 4) ? 61 : 0;
            R[r * 16 + (tid & 15)] = make_float4(0, 0, 0, 0);
        }
        const float4* bp = (const float4*)(bs + (size_t)f * (C_ * KD * PLANE));
#pragma unroll
        for (int k = 0; k < 4; ++k) {
            const int e = tid + 256 * k;
            if (e < NCH) {
                float4 s = make_float4(0, 0, 0, 0);
#pragma unroll
                for (int s6 = 0; s6 < 6; ++s6) add4(s, bp[s6 * NCH + e]);
                R[((e >> 4) + 1) * 16 + (e & 15)] = s;
            }
        }
        __syncthreads();
        float4* ob = (float4*)(bb + (size_t)f * PLANE);
#pragma unroll
        for (int k = 0; k < 4; ++k) {
            const int e = tid + 256 * k;
            if (e < NCH) {
                const int row = e >> 4, c4 = e & 15;
                const float4 a = R[row * 16 + c4];
                const float4 m = R[(row + 1) * 16 + c4];
                const float4 d = R[(row + 2) * 16 + c4];
                float4 V;
                V.x = a.x + m.x + d.x; V.y = a.y + m.y + d.y;
                V.z = a.z + m.z + d.z; V.w = a.w + m.w + d.w;
                ob[e] = hsum3(V, c4);
            }
        }
    }
}

// ---------------------------------------------------------------------------
// Main kernel (unchanged from R8: plane-major accumulation, 5 blocks/CU).
//  * Block = (b, f, tile, half); half owns 30 output rows, 32 acc rows
//    (1-row halo); ONE barrier per block; b = bx&7 XCD pin.
//  * Plane-major: 6 distinct planes per c loaded ONCE each, scatter-FMA into
//    acc[td = pi - z]; per-accumulator FP-op order identical to R4.
//  * __launch_bounds__(256,5): VGPR 84 <= 102 cap, LDS 5 x 32 KB = 160 KB.
//  * Epilogue verbatim R4; plain coalesced float4 stores (NO nontemporal:
//    NT amplified HBM writes +52 MB in both R1 and R5).
// ---------------------------------------------------------------------------
__global__ __launch_bounds__(256, 5) void k_main(const float* __restrict__ s2,
                                                 const float* __restrict__ wt,
                                                 const float* __restrict__ bb,
                                                 float* __restrict__ out) {
    const int bx = blockIdx.x;
    const int b = bx & 7;            // XCD-pinned batch index
    const int f = (bx >> 3) & 7;
    const int half = (bx >> 6) & 1;
    const int tile = bx >> 7;        // 0..23
    const int d0 = tile * TD;
    const int t = threadIdx.x;
    const int col4 = t & 15;
    const int lr = t >> 4;           // local row 0..15

    // global acc rows: chunk A = gbase+lr, chunk B = gbase+lr+16
    const int gbase = half * 30 - 1;      // -1 or 29
    const int gA = gbase + lr;            // [-1..45]
    const int gB = gA + 16;               // [15..60]
    const bool vA = (gA >= 0) && (gA <= h_ - 1);
    const bool vB = (gB >= 0) && (gB <= h_ - 1);
    const int cgA = min(max(gA, 0), h_ - 1);
    const int cgB = min(max(gB, 0), h_ - 1);
    const int eA = cgA * 16 + col4;       // clamped plane chunk index
    const int eB = cgB * 16 + col4;

    __shared__ float4 Lds[TD][512];       // 32 KB

    // loop-invariant caches: weights 12 float4 (48 regs) + boxed bias (8 regs)
    const float4* wp = (const float4*)(wt + (size_t)f * (C_ * KD * PLANE));
    const float4* bbp = (const float4*)(bb + (size_t)f * PLANE);
    float4 wrA[6], wrB[6];
#pragma unroll
    for (int s6 = 0; s6 < 6; ++s6) {
        wrA[s6] = wp[s6 * NCH + eA];
        wrB[s6] = wp[s6 * NCH + eB];
    }
    const float4 bbA = bbp[eA];
    const float4 bbB = bbp[eB];

    const float4* s2b = (const float4*)s2 + (size_t)(b * C_) * D_ * NCH;
    float* ob = out + (size_t)((b * F_ + f) * Dout_) * PLANE;

    // ---- phase 1: plane-major accumulation, each plane loaded ONCE ----
    float4 accA[TD], accB[TD];
#pragma unroll
    for (int td = 0; td < TD; ++td) {
        accA[td] = make_float4(0, 0, 0, 0);
        accB[td] = make_float4(0, 0, 0, 0);
    }

#pragma unroll
    for (int c = 0; c < C_; ++c)
#pragma unroll
        for (int pi = 0; pi < TD + 2; ++pi) {
            int p = d0 + pi;
            if (p > D_ - 1) p = D_ - 1;   // clamped planes feed only discarded
            const float4* sp = s2b + (size_t)(c * D_ + p) * NCH;  // tail douts
            const float4 sAv = sp[eA];
            const float4 sBv = sp[eB];
#pragma unroll
            for (int z = 0; z < KD; ++z) {
                const int td = pi - z;
                if (td >= 0 && td < TD) {
                    fma4(accA[td], sAv, wrA[c * KD + z]);
                    fma4(accB[td], sBv, wrB[c * KD + z]);
                }
            }
        }

#pragma unroll
    for (int td = 0; td < TD; ++td) {
        if (!vA) accA[td] = make_float4(0, 0, 0, 0);   // halo pad rows are zero
        if (!vB) accB[td] = make_float4(0, 0, 0, 0);
        Lds[td][t] = accA[td];        // local chunk A = lr*16+col4 = t
        Lds[td][t + 256] = accB[td];  // local chunk B
    }
    __syncthreads();   // the ONE barrier per block

    // ---- phase 2: TD epilogues (verbatim R4) ----
    const bool sA = (lr >= 1);                 // owns output row gA
    const bool sB = (lr <= 14);                // owns output row gB
    const int iuA = (lr == 0) ? t : t - 16;    // clamp (discarded anyway)
    const int idB = (lr == 15) ? t + 256 : t + 272;
    const int oA = gA * 16 + col4;
    const int oB = gB * 16 + col4;

#pragma unroll
    for (int td = 0; td < TD; ++td) {
        const int dout = d0 + td;

        // chunk A vertical 3-tap
        const float4 uA = Lds[td][iuA];
        const float4 mA = Lds[td][t];
        const float4 dA = Lds[td][t + 16];     // lr=15 -> chunk B row 16: valid
        float4 VA;
        VA.x = uA.x + mA.x + dA.x; VA.y = uA.y + mA.y + dA.y;
        VA.z = uA.z + mA.z + dA.z; VA.w = uA.w + mA.w + dA.w;
        float4 rA = hsum3(VA, col4);

        // chunk B vertical 3-tap
        const float4 uB = Lds[td][t + 240];    // chunk A row lr+15: valid
        const float4 mB = Lds[td][t + 256];
        const float4 dB = Lds[td][idB];
        float4 VB;
        VB.x = uB.x + mB.x + dB.x; VB.y = uB.y + mB.y + dB.y;
        VB.z = uB.z + mB.z + dB.z; VB.w = uB.w + mB.w + dB.w;
        float4 rB = hsum3(VB, col4);

        rA.x = 0.25f * (rA.x + bbA.x); rA.y = 0.25f * (rA.y + bbA.y);
        rA.z = 0.25f * (rA.z + bbA.z); rA.w = 0.25f * (rA.w + bbA.w);
        rB.x = 0.25f * (rB.x + bbB.x); rB.y = 0.25f * (rB.y + bbB.y);
        rB.z = 0.25f * (rB.z + bbB.z); rB.w = 0.25f * (rB.w + bbB.w);
        rA.x = (rA.x > 0.f) ? rA.x : 0.2f * rA.x;
        rA.y = (rA.y > 0.f) ? rA.y : 0.2f * rA.y;
        rA.z = (rA.z > 0.f) ? rA.z : 0.2f * rA.z;
        rA.w = (rA.w > 0.f) ? rA.w : 0.2f * rA.w;
        rB.x = (rB.x > 0.f) ? rB.x : 0.2f * rB.x;
        rB.y = (rB.y > 0.f) ? rB.y : 0.2f * rB.y;
        rB.z = (rB.z > 0.f) ? rB.z : 0.2f * rB.z;
        rB.w = (rB.w > 0.f) ? rB.w : 0.2f * rB.w;

        if (dout < Dout_) {
            float4* od4 = (float4*)(ob + (size_t)dout * PLANE);
            if (sA) od4[oA] = rA;
            if (sB) od4[oB] = rB;
        }
    }
}

extern "C" void kernel_launch(void* const* d_in, const int* in_sizes, int n_in,
                              void* d_out, int out_size, void* d_ws, size_t ws_size,
                              hipStream_t stream) {
    const float* in = (const float*)d_in[0];
    const float* wt = (const float*)d_in[1];
    const float* bs = (const float*)d_in[2];
    float* out = (float*)d_out;

    float* s2 = (float*)d_ws;
    float* bb = s2 + S2_FLOATS;

    k_prep<<<dim3(NS2 + F_), dim3(256), 0, stream>>>(in, bs, s2, bb);
    k_main<<<dim3(B_ * F_ * NTILE * 2), dim3(256), 0, stream>>>(s2, wt, bb, out);
}

// Round 10
// 132.750 us; speedup vs baseline: 1.0143x; 1.0143x over previous
//
#include <hip/hip_runtime.h>

// Problem constants:
// inputs: (B=8, C=2, D=96, H=64, W=64) f32
// weight/bias: (F=8, C=2, d=3, h=60, w=64) f32
// out: (B=8, F=8, Dout=94, h=60, w=64) f32
#define B_ 8
#define C_ 2
#define D_ 96
#define H_ 64
#define W_ 64
#define F_ 8
#define KD 3
#define h_ 60
#define Dout_ 94
#define PLANE (h_ * W_)          // 3840 floats
#define NCH (PLANE / 4)          // 960 float4 chunks
#define TD 4                     // douts batched per block (ONE barrier per batch)
#define NTILE ((Dout_ + TD - 1) / TD)  // 24
#define NS2 (B_ * C_ * D_)       // 1536 s2 planes
#define S2_FLOATS ((size_t)NS2 * PLANE)

__device__ __forceinline__ void fma4(float4& a, const float4 v, const float4 g) {
    a.x += v.x * g.x; a.y += v.y * g.y;
    a.z += v.z * g.z; a.w += v.w * g.w;
}

__device__ __forceinline__ void add4(float4& a, const float4 v) {
    a.x += v.x; a.y += v.y; a.z += v.z; a.w += v.w;
}

// Horizontal 3-tap sum via lane shuffles; col4 = position 0..15 within a
// 16-lane row group. Boundary cols contribute zero. All 64 lanes must execute.
__device__ __forceinline__ float4 hsum3(float4 V, int col4) {
    const int lane = threadIdx.x & 63;
    float lw = __shfl(V.w, (lane + 63) & 63, 64);
    float rx = __shfl(V.x, (lane + 1) & 63, 64);
    if (col4 == 0) lw = 0.f;
    if (col4 == 15) rx = 0.f;
    float4 o;
    o.x = lw + V.x + V.y;
    o.y = V.x + V.y + V.z;
    o.z = V.y + V.z + V.w;
    o.w = V.z + V.w + rx;
    return o;
}

// ---------------------------------------------------------------------------
// Prep kernel (reverted to R8's proven version; R9's XCD remap was neutral-
// to-negative — the output write stream evicts dirty S2 from L2 anyway).
// Blocks 0..NS2-1: S2[b,c,p] = vertical 5-sum of input plane (no LDS/barrier).
// Blocks NS2..NS2+F_-1: BoxBS[f] = Box3x3( sum_{c,z} bias[f,c,z] ).
// ---------------------------------------------------------------------------
__global__ __launch_bounds__(256) void k_prep(const float* __restrict__ in,
                                              const float* __restrict__ bs,
                                              float* __restrict__ s2,
                                              float* __restrict__ bb) {
    const int bx = blockIdx.x;
    const int tid = threadIdx.x;
    __shared__ float4 lds[H_ * 16];  // used by bias path only (16 KB)

    if (bx < NS2) {
        const int col4 = tid & 15;
        const int seg = tid >> 4;         // 0..15; seg 15 idle (15*4 = 60 rows)
        if (seg >= 15) return;
        const int r0 = seg * 4;
        const float4* ip4 = (const float4*)(in + (size_t)bx * (H_ * W_));
        float4* op4 = (float4*)(s2 + (size_t)bx * PLANE);
        float4 v[8];
#pragma unroll
        for (int j = 0; j < 8; ++j) v[j] = ip4[(r0 + j) * 16 + col4];
#pragma unroll
        for (int r = 0; r < 4; ++r) {
            float4 s = v[r];
#pragma unroll
            for (int j = 1; j < 5; ++j) add4(s, v[r + j]);
            op4[(r0 + r) * 16 + col4] = s;
        }
    } else {
        const int f = bx - NS2;
        float4* R = lds;  // rows 0..61, rows 0 and 61 zero
        if (tid < 32) {
            const int r = (tid >> 4) ? 61 : 0;
            R[r * 16 + (tid & 15)] = make_float4(0, 0, 0, 0);
        }
        const float4* bp = (const float4*)(bs + (size_t)f * (C_ * KD * PLANE));
#pragma unroll
        for (int k = 0; k < 4; ++k) {
            const int e = tid + 256 * k;
            if (e < NCH) {
                float4 s = make_float4(0, 0, 0, 0);
#pragma unroll
                for (int s6 = 0; s6 < 6; ++s6) add4(s, bp[s6 * NCH + e]);
                R[((e >> 4) + 1) * 16 + (e & 15)] = s;
            }
        }
        __syncthreads();
        float4* ob = (float4*)(bb + (size_t)f * PLANE);
#pragma unroll
        for (int k = 0; k < 4; ++k) {
            const int e = tid + 256 * k;
            if (e < NCH) {
                const int row = e >> 4, c4 = e & 15;
                const float4 a = R[row * 16 + c4];
                const float4 m = R[(row + 1) * 16 + c4];
                const float4 d = R[(row + 2) * 16 + c4];
                float4 V;
                V.x = a.x + m.x + d.x; V.y = a.y + m.y + d.y;
                V.z = a.z + m.z + d.z; V.w = a.w + m.w + d.w;
                ob[e] = hsum3(V, c4);
            }
        }
    }
}

// ---------------------------------------------------------------------------
// Main kernel (R10: filter-paired, 512 threads, 1 chunk/thread).
//  * Block = (b, f-pair, tile, half). The 32-row acc slab = exactly 512
//    chunks -> thread t owns chunk e(t) (row r32 = t>>4, col4 = t&15).
//  * Each thread loads its 12 distinct S2 plane-values ONCE and FMAs them
//    into accumulators for BOTH filters of the pair: S2 L2-request traffic
//    halves (302 -> 151 MB total). Weight/bias/output traffic unchanged.
//  * Per-accumulator FP-op order identical to R8 (c-major, z-ascending) ->
//    bit-identical numerics. Epilogue logic identical (middle tap from regs,
//    hsum3, +bb, *0.25, leaky, plain coalesced stores — NO nontemporal).
//  * LDS 2f x TD x 512 f4 = 64 KB; regs ~112 est (< 128 cap of (512,4));
//    2 blocks/CU = 16 waves/CU (vs R8's 20) — the traded quantity.
//  * ONE barrier per block, 1536 blocks, XCD pin b = bx&7.
// ---------------------------------------------------------------------------
__global__ __launch_bounds__(512, 4) void k_main(const float* __restrict__ s2,
                                                 const float* __restrict__ wt,
                                                 const float* __restrict__ bb,
                                                 float* __restrict__ out) {
    const int bx = blockIdx.x;
    const int b = bx & 7;            // XCD-pinned batch index
    const int f2 = (bx >> 3) & 3;    // filter pair 0..3
    const int half = (bx >> 5) & 1;
    const int tile = bx >> 6;        // 0..23
    const int d0 = tile * TD;
    const int f0 = f2 * 2;
    const int t = threadIdx.x;       // 0..511
    const int col4 = t & 15;
    const int r32 = t >> 4;          // slab row 0..31

    // global acc row for this thread's chunk
    const int gbase = half * 30 - 1;       // -1 or 29
    const int g = gbase + r32;             // [-1..60]
    const bool vG = (g >= 0) && (g <= h_ - 1);
    const int cg = min(max(g, 0), h_ - 1);
    const int e = cg * 16 + col4;          // clamped plane chunk index

    __shared__ float4 SL[2][TD][512];      // 64 KB: [filter][td][chunk]

    // loop-invariant caches: weights 2x6 f4 (96 regs... 48 each) + bias 2 f4
    float4 wr[2][6];
    float4 bb2[2];
#pragma unroll
    for (int ff = 0; ff < 2; ++ff) {
        const float4* wp = (const float4*)(wt + (size_t)(f0 + ff) * (C_ * KD * PLANE));
#pragma unroll
        for (int s6 = 0; s6 < 6; ++s6) wr[ff][s6] = wp[s6 * NCH + e];
        bb2[ff] = ((const float4*)(bb + (size_t)(f0 + ff) * PLANE))[e];
    }

    const float4* s2b = (const float4*)s2 + (size_t)(b * C_) * D_ * NCH;

    // ---- phase 1: plane-major; each of the 12 planes loaded ONCE,
    //      scatter-FMA into both filters' acc[td = pi - z] ----
    float4 acc[2][TD];
#pragma unroll
    for (int ff = 0; ff < 2; ++ff)
#pragma unroll
        for (int td = 0; td < TD; ++td) acc[ff][td] = make_float4(0, 0, 0, 0);

#pragma unroll
    for (int c = 0; c < C_; ++c)
#pragma unroll
        for (int pi = 0; pi < TD + 2; ++pi) {
            int p = d0 + pi;
            if (p > D_ - 1) p = D_ - 1;    // clamped planes feed only discarded douts
            const float4 v = (s2b + (size_t)(c * D_ + p) * NCH)[e];
#pragma unroll
            for (int z = 0; z < KD; ++z) {
                const int td = pi - z;
                if (td >= 0 && td < TD) {
                    fma4(acc[0][td], v, wr[0][c * KD + z]);
                    fma4(acc[1][td], v, wr[1][c * KD + z]);
                }
            }
        }

#pragma unroll
    for (int ff = 0; ff < 2; ++ff)
#pragma unroll
        for (int td = 0; td < TD; ++td) {
            if (!vG) acc[ff][td] = make_float4(0, 0, 0, 0);  // halo pads zero
            SL[ff][td][t] = acc[ff][td];
        }
    __syncthreads();   // the ONE barrier per block

    // ---- phase 2: epilogues for both filters (middle tap from regs) ----
    const bool own = (r32 >= 1) && (r32 <= 30);   // owned output rows
    const int iu = (r32 == 0) ? t : t - 16;       // clamped (non-owned lanes)
    const int id = (r32 == 31) ? t : t + 16;
    const int oE = g * 16 + col4;

#pragma unroll
    for (int ff = 0; ff < 2; ++ff) {
        float* ob = out + (size_t)((b * F_ + f0 + ff) * Dout_) * PLANE;
#pragma unroll
        for (int td = 0; td < TD; ++td) {
            const int dout = d0 + td;

            const float4 u = SL[ff][td][iu];
            const float4 m = acc[ff][td];
            const float4 dn = SL[ff][td][id];
            float4 V;
            V.x = u.x + m.x + dn.x; V.y = u.y + m.y + dn.y;
            V.z = u.z + m.z + dn.z; V.w = u.w + m.w + dn.w;
            float4 r = hsum3(V, col4);

            r.x = 0.25f * (r.x + bb2[ff].x); r.y = 0.25f * (r.y + bb2[ff].y);
            r.z = 0.25f * (r.z + bb2[ff].z); r.w = 0.25f * (r.w + bb2[ff].w);
            r.x = (r.x > 0.f) ? r.x : 0.2f * r.x;
            r.y = (r.y > 0.f) ? r.y : 0.2f * r.y;
            r.z = (r.z > 0.f) ? r.z : 0.2f * r.z;
            r.w = (r.w > 0.f) ? r.w : 0.2f * r.w;

            if (own && dout < Dout_) {
                float4* od4 = (float4*)(ob + (size_t)dout * PLANE);
                od4[oE] = r;
            }
        }
    }
}

extern "C" void kernel_launch(void* const* d_in, const int* in_sizes, int n_in,
                              void* d_out, int out_size, void* d_ws, size_t ws_size,
                              hipStream_t stream) {
    const float* in = (const float*)d_in[0];
    const float* wt = (const float*)d_in[1];
    const float* bs = (const float*)d_in[2];
    float* out = (float*)d_out;

    float* s2 = (float*)d_ws;
    float* bb = s2 + S2_FLOATS;

    k_prep<<<dim3(NS2 + F_), dim3(256), 0, stream>>>(in, bs, s2, bb);
    k_main<<<dim3(B_ * (F_ / 2) * NTILE * 2), dim3(512), 0, stream>>>(s2, wt, bb, out);
}